// Round 7
// baseline (279.845 us; speedup 1.0000x reference)
//
#include <hip/hip_runtime.h>
#include <hip/hip_bf16.h>

// QuantLinearAWQ: out[T,N] = x[T,K] @ ((q - z) * s)[K,N] + bias[N]
// T=32, K=4096, N=11008, group=128.
// R6 -> R7: fp16 error (0.625) == bf16 error (0.588) -> R5's ~0.6 error is
// a DETERMINISTIC bug in the R5 remap/vector-load restructure, not rounding.
// Bisect: revert to the exact R4 structure (verified, absmax 0.125) with ONE
// change: bf16 -> fp16 MFMA (8x finer mantissa -> expected absmax ~0.03,
// 15x margin). Next round re-adds the coalescing remap as the sole delta.

#define TOKENS   32
#define KDIM     4096
#define NDIM     11008
#define GS       128
#define KSPLIT   32
#define KCHUNK   128               // == GS: one quant group per k-block
#define BLOCK    256               // 4 waves
#define WAVE_N   64                // 4 n-tiles of 16 per wave
#define BLOCK_N  256               // 43 * 256 == 11008 exactly

typedef __attribute__((ext_vector_type(8))) _Float16 half8;  // MFMA A/B
typedef __attribute__((ext_vector_type(4))) float   floatx4; // MFMA C/D

// ---------- x fp32 -> fp16 (256 KB, L2-resident during gemm) ----------
__global__ __launch_bounds__(256) void awq_cvt_kernel(
    const float* __restrict__ x, unsigned short* __restrict__ xh)
{
    const int i = blockIdx.x * 256 + threadIdx.x;      // grid 128: 32768 float4s
    const float4 v = ((const float4*)x)[i];
    ushort4 o;
    o.x = __builtin_bit_cast(unsigned short, (_Float16)v.x);
    o.y = __builtin_bit_cast(unsigned short, (_Float16)v.y);
    o.z = __builtin_bit_cast(unsigned short, (_Float16)v.z);
    o.w = __builtin_bit_cast(unsigned short, (_Float16)v.w);
    ((ushort4*)xh)[i] = o;
}

// ---------- bias init (atomic-fallback path only) ----------
__global__ __launch_bounds__(256) void awq_init_kernel(
    const float* __restrict__ bias, float* __restrict__ out)
{
    const int n = blockIdx.x * 256 + threadIdx.x;      // grid (43, 32)
    out[blockIdx.y * NDIM + n] = bias[n];
}

// ---------- MFMA dequant-GEMM (R4-verified layout) ----------
// A-frag: A[m=lane&15][k=quad*8+j]; C/D: col=lane&15, row=quad*4+reg.
// B symmetric to A: B[k=quad*8+j][n=lane&15]. n = nb + nt*16 + col.
template<bool ATOMIC>
__global__ __launch_bounds__(BLOCK) void awq_gemm_mfma(
    const unsigned short* __restrict__ xh,   // [T][K] fp16 bits
    const int*   __restrict__ qw,            // [K][N] codes
    const int*   __restrict__ qz,            // [K/GS][N]
    const float* __restrict__ sc,            // [K/GS][N]
    float*       __restrict__ dst)           // part [KSPLIT][T][N] or out [T][N]
{
    const int tid  = threadIdx.x;
    const int lane = tid & 63;
    const int wv   = tid >> 6;               // 0..3
    const int col  = lane & 15;
    const int quad = lane >> 4;              // 0..3
    const int g    = blockIdx.y;             // group index == k-split index
    const int kc0  = g * KCHUNK;
    const int nb   = blockIdx.x * BLOCK_N + wv * WAVE_N;

    // per-n-tile scale / fused zero: w = q*s + (-z*s)  ((q-8)-(z-8) == q-z)
    float s[4], nzs[4];
    #pragma unroll
    for (int nt = 0; nt < 4; ++nt) {
        const int n  = nb + nt * 16 + col;
        const float sv = sc[(size_t)g * NDIM + n];
        const int   zv = qz[(size_t)g * NDIM + n];
        s[nt] = sv; nzs[nt] = -(float)zv * sv;
    }

    floatx4 acc[4][2];
    #pragma unroll
    for (int nt = 0; nt < 4; ++nt) {
        acc[nt][0] = (floatx4){0.f, 0.f, 0.f, 0.f};
        acc[nt][1] = (floatx4){0.f, 0.f, 0.f, 0.f};
    }

    const int* qp = qw + (size_t)(kc0 + quad * 8) * NDIM + nb + col;
    const unsigned short* xr0 = xh + (size_t)col * KDIM + kc0 + quad * 8;
    const unsigned short* xr1 = xr0 + 16 * KDIM;   // tokens 16-31

    #pragma unroll 2
    for (int ks = 0; ks < KCHUNK / 32; ++ks) {   // 4 k-steps of 32
        // issue all 32 weight loads first (latency overlap)
        int q[4][8];
        #pragma unroll
        for (int nt = 0; nt < 4; ++nt)
            #pragma unroll
            for (int j = 0; j < 8; ++j)
                q[nt][j] = qp[(ks * 32 + j) * NDIM + nt * 16];

        const half8 a0 = *(const half8*)(xr0 + ks * 32);   // tokens 0-15
        const half8 a1 = *(const half8*)(xr1 + ks * 32);   // tokens 16-31

        #pragma unroll
        for (int nt = 0; nt < 4; ++nt) {
            half8 b;
            #pragma unroll
            for (int j = 0; j < 8; ++j)
                b[j] = (_Float16)fmaf((float)q[nt][j], s[nt], nzs[nt]);
            acc[nt][0] = __builtin_amdgcn_mfma_f32_16x16x32_f16(a0, b, acc[nt][0], 0, 0, 0);
            acc[nt][1] = __builtin_amdgcn_mfma_f32_16x16x32_f16(a1, b, acc[nt][1], 0, 0, 0);
        }
    }

    // C/D: token = h*16 + quad*4 + r, n = nb + nt*16 + col
    if (ATOMIC) {
        #pragma unroll
        for (int nt = 0; nt < 4; ++nt)
            #pragma unroll
            for (int h = 0; h < 2; ++h) {
                float* pp = dst + (size_t)(h * 16 + quad * 4) * NDIM + nb + nt * 16 + col;
                #pragma unroll
                for (int r = 0; r < 4; ++r)
                    unsafeAtomicAdd(pp + (size_t)r * NDIM, acc[nt][h][r]);
            }
    } else {
        float* pbase = dst + (size_t)g * TOKENS * NDIM;
        #pragma unroll
        for (int nt = 0; nt < 4; ++nt)
            #pragma unroll
            for (int h = 0; h < 2; ++h) {
                float* pp = pbase + (size_t)(h * 16 + quad * 4) * NDIM + nb + nt * 16 + col;
                #pragma unroll
                for (int r = 0; r < 4; ++r)
                    pp[(size_t)r * NDIM] = acc[nt][h][r];
            }
    }
}

// ---------- reduce KSPLIT partials + bias ----------
__global__ __launch_bounds__(256) void awq_reduce_kernel(
    const float* __restrict__ part,   // [KSPLIT][T][N]
    const float* __restrict__ bias,
    float*       __restrict__ out)    // [T][N]
{
    const int o = blockIdx.x * 256 + threadIdx.x;   // float4 idx, 88064 total
    const int t = o / (NDIM / 4);
    const int c = o - t * (NDIM / 4);
    const float4* p4 = (const float4*)part;
    float4 sum = ((const float4*)bias)[c];
    #pragma unroll 8
    for (int s = 0; s < KSPLIT; ++s) {
        const float4 v = p4[(size_t)(s * TOKENS + t) * (NDIM / 4) + c];
        sum.x += v.x; sum.y += v.y; sum.z += v.z; sum.w += v.w;
    }
    ((float4*)out)[o] = sum;
}

extern "C" void kernel_launch(void* const* d_in, const int* in_sizes, int n_in,
                              void* d_out, int out_size, void* d_ws, size_t ws_size,
                              hipStream_t stream) {
    const float* x    = (const float*)d_in[0];
    const int*   qw   = (const int*)  d_in[1];
    const int*   qz   = (const int*)  d_in[2];
    const float* sc   = (const float*)d_in[3];
    const float* bias = (const float*)d_in[4];
    float* out = (float*)d_out;

    const size_t xh_bytes   = 512 * 1024;  // 256 KB used, padded
    const size_t part_bytes = (size_t)KSPLIT * TOKENS * NDIM * sizeof(float); // 45 MB
    unsigned short* xh = (unsigned short*)d_ws;
    float* part = (float*)((char*)d_ws + xh_bytes);

    awq_cvt_kernel<<<(TOKENS * KDIM / 4) / 256, 256, 0, stream>>>(x, xh);

    if (ws_size >= xh_bytes + part_bytes) {
        awq_gemm_mfma<false><<<dim3(NDIM / BLOCK_N, KSPLIT), BLOCK, 0, stream>>>(
            xh, qw, qz, sc, part);
        awq_reduce_kernel<<<(TOKENS * NDIM / 4) / 256, 256, 0, stream>>>(
            part, bias, out);
    } else {
        awq_init_kernel<<<dim3(NDIM / 256, TOKENS), 256, 0, stream>>>(bias, out);
        awq_gemm_mfma<true><<<dim3(NDIM / BLOCK_N, KSPLIT), BLOCK, 0, stream>>>(
            xh, qw, qz, sc, out);
    }
}

// Round 8
// 278.429 us; speedup vs baseline: 1.0051x; 1.0051x over previous
//
#include <hip/hip_runtime.h>
#include <hip/hip_bf16.h>

// QuantLinearAWQ: out[T,N] = x[T,K] @ ((q - z) * s)[K,N] + bias[N]
// T=32, K=4096, N=11008, group=128.
// R7 -> R8: proper single-delta bisect. R7 (PASS 0.125) + ONLY the
// weight-access bundle from R5: column remap n = nb + 4*col + nt, int4
// 16B/lane weight loads, float4 C-stores. KSPLIT=32, KCHUNK=128, no
// gi-loop, scalar s/z loads -- all R7-identical. PASS -> R5 bug was in the
// KSPLIT16/gi half + we bank 4x fewer VMEM instrs. FAIL ~0.6 -> remap core
// definitively guilty; next round uses LDS staging instead.

#define TOKENS   32
#define KDIM     4096
#define NDIM     11008
#define GS       128
#define KSPLIT   32
#define KCHUNK   128               // == GS: one quant group per k-block
#define BLOCK    256               // 4 waves
#define BLOCK_N  256               // 43 * 256 == 11008 exactly

typedef __attribute__((ext_vector_type(8))) _Float16 half8;  // MFMA A/B
typedef __attribute__((ext_vector_type(4))) float   floatx4; // MFMA C/D

// ---------- x fp32 -> fp16 (256 KB, L2-resident during gemm) ----------
__global__ __launch_bounds__(256) void awq_cvt_kernel(
    const float* __restrict__ x, unsigned short* __restrict__ xh)
{
    const int i = blockIdx.x * 256 + threadIdx.x;      // grid 128: 32768 float4s
    const float4 v = ((const float4*)x)[i];
    ushort4 o;
    o.x = __builtin_bit_cast(unsigned short, (_Float16)v.x);
    o.y = __builtin_bit_cast(unsigned short, (_Float16)v.y);
    o.z = __builtin_bit_cast(unsigned short, (_Float16)v.z);
    o.w = __builtin_bit_cast(unsigned short, (_Float16)v.w);
    ((ushort4*)xh)[i] = o;
}

// ---------- bias init (atomic-fallback path only) ----------
__global__ __launch_bounds__(256) void awq_init_kernel(
    const float* __restrict__ bias, float* __restrict__ out)
{
    const int n = blockIdx.x * 256 + threadIdx.x;      // grid (43, 32)
    out[blockIdx.y * NDIM + n] = bias[n];
}

// ---------- MFMA dequant-GEMM ----------
// A-frag: A[m=lane&15][k=quad*8+j]; C/D: col=lane&15, row=quad*4+reg.
// B symmetric to A. Column remap: MFMA-tile nt, MFMA-col c -> memory column
// n = nb + 4*c + nt, so one int4 per (k-row, lane) feeds all 4 tiles.
template<bool ATOMIC>
__global__ __launch_bounds__(BLOCK) void awq_gemm_mfma(
    const unsigned short* __restrict__ xh,   // [T][K] fp16 bits
    const int*   __restrict__ qw,            // [K][N] codes
    const int*   __restrict__ qz,            // [K/GS][N]
    const float* __restrict__ sc,            // [K/GS][N]
    float*       __restrict__ dst)           // part [KSPLIT][T][N] or out [T][N]
{
    const int tid  = threadIdx.x;
    const int lane = tid & 63;
    const int wv   = tid >> 6;               // 0..3
    const int col  = lane & 15;
    const int quad = lane >> 4;              // 0..3
    const int g    = blockIdx.y;             // group index == k-split index
    const int kc0  = g * KCHUNK;
    const int nb   = blockIdx.x * BLOCK_N + wv * 64;
    const int nc   = nb + 4 * col;           // 4 consecutive columns per lane

    // scalar s/z loads (R7-style) at the remapped columns
    float s[4], nzs[4];
    #pragma unroll
    for (int nt = 0; nt < 4; ++nt) {
        const int n  = nc + nt;
        const float sv = sc[(size_t)g * NDIM + n];
        const int   zv = qz[(size_t)g * NDIM + n];
        s[nt] = sv; nzs[nt] = -(float)zv * sv;   // (q-8)-(z-8) == q-z
    }

    floatx4 acc[4][2];
    #pragma unroll
    for (int nt = 0; nt < 4; ++nt) {
        acc[nt][0] = (floatx4){0.f, 0.f, 0.f, 0.f};
        acc[nt][1] = (floatx4){0.f, 0.f, 0.f, 0.f};
    }

    const int* qbase = qw + (size_t)(kc0 + quad * 8) * NDIM + nc;
    const unsigned short* xr0 = xh + (size_t)col * KDIM + kc0 + quad * 8;
    const unsigned short* xr1 = xr0 + 16 * KDIM;   // tokens 16-31

    #pragma unroll 2
    for (int ks = 0; ks < KCHUNK / 32; ++ks) {   // 4 k-steps of 32
        // 8 x dwordx4: 16B/lane, 256B contiguous per quad-row
        int4 q[8];
        #pragma unroll
        for (int j = 0; j < 8; ++j)
            q[j] = *(const int4*)(qbase + (size_t)(ks * 32 + j) * NDIM);

        const half8 a0 = *(const half8*)(xr0 + ks * 32);   // tokens 0-15
        const half8 a1 = *(const half8*)(xr1 + ks * 32);   // tokens 16-31

        half8 b0, b1, b2, b3;
        #pragma unroll
        for (int j = 0; j < 8; ++j) {
            b0[j] = (_Float16)fmaf((float)q[j].x, s[0], nzs[0]);
            b1[j] = (_Float16)fmaf((float)q[j].y, s[1], nzs[1]);
            b2[j] = (_Float16)fmaf((float)q[j].z, s[2], nzs[2]);
            b3[j] = (_Float16)fmaf((float)q[j].w, s[3], nzs[3]);
        }
        acc[0][0] = __builtin_amdgcn_mfma_f32_16x16x32_f16(a0, b0, acc[0][0], 0, 0, 0);
        acc[0][1] = __builtin_amdgcn_mfma_f32_16x16x32_f16(a1, b0, acc[0][1], 0, 0, 0);
        acc[1][0] = __builtin_amdgcn_mfma_f32_16x16x32_f16(a0, b1, acc[1][0], 0, 0, 0);
        acc[1][1] = __builtin_amdgcn_mfma_f32_16x16x32_f16(a1, b1, acc[1][1], 0, 0, 0);
        acc[2][0] = __builtin_amdgcn_mfma_f32_16x16x32_f16(a0, b2, acc[2][0], 0, 0, 0);
        acc[2][1] = __builtin_amdgcn_mfma_f32_16x16x32_f16(a1, b2, acc[2][1], 0, 0, 0);
        acc[3][0] = __builtin_amdgcn_mfma_f32_16x16x32_f16(a0, b3, acc[3][0], 0, 0, 0);
        acc[3][1] = __builtin_amdgcn_mfma_f32_16x16x32_f16(a1, b3, acc[3][1], 0, 0, 0);
    }

    // token = h*16 + quad*4 + r; columns nc..nc+3 = tiles 0..3 -> float4
    if (ATOMIC) {
        #pragma unroll
        for (int h = 0; h < 2; ++h)
            #pragma unroll
            for (int r = 0; r < 4; ++r) {
                float* pp = dst + (size_t)(h * 16 + quad * 4 + r) * NDIM + nc;
                unsafeAtomicAdd(pp + 0, acc[0][h][r]);
                unsafeAtomicAdd(pp + 1, acc[1][h][r]);
                unsafeAtomicAdd(pp + 2, acc[2][h][r]);
                unsafeAtomicAdd(pp + 3, acc[3][h][r]);
            }
    } else {
        float* pbase = dst + (size_t)g * TOKENS * NDIM;
        #pragma unroll
        for (int h = 0; h < 2; ++h)
            #pragma unroll
            for (int r = 0; r < 4; ++r) {
                const float4 v = make_float4(acc[0][h][r], acc[1][h][r],
                                             acc[2][h][r], acc[3][h][r]);
                *(float4*)(pbase + (size_t)(h * 16 + quad * 4 + r) * NDIM + nc) = v;
            }
    }
}

// ---------- reduce KSPLIT partials + bias ----------
__global__ __launch_bounds__(256) void awq_reduce_kernel(
    const float* __restrict__ part,   // [KSPLIT][T][N]
    const float* __restrict__ bias,
    float*       __restrict__ out)    // [T][N]
{
    const int o = blockIdx.x * 256 + threadIdx.x;   // float4 idx, 88064 total
    const int t = o / (NDIM / 4);
    const int c = o - t * (NDIM / 4);
    const float4* p4 = (const float4*)part;
    float4 sum = ((const float4*)bias)[c];
    #pragma unroll 8
    for (int s = 0; s < KSPLIT; ++s) {
        const float4 v = p4[(size_t)(s * TOKENS + t) * (NDIM / 4) + c];
        sum.x += v.x; sum.y += v.y; sum.z += v.z; sum.w += v.w;
    }
    ((float4*)out)[o] = sum;
}

extern "C" void kernel_launch(void* const* d_in, const int* in_sizes, int n_in,
                              void* d_out, int out_size, void* d_ws, size_t ws_size,
                              hipStream_t stream) {
    const float* x    = (const float*)d_in[0];
    const int*   qw   = (const int*)  d_in[1];
    const int*   qz   = (const int*)  d_in[2];
    const float* sc   = (const float*)d_in[3];
    const float* bias = (const float*)d_in[4];
    float* out = (float*)d_out;

    const size_t xh_bytes   = 512 * 1024;  // 256 KB used, padded
    const size_t part_bytes = (size_t)KSPLIT * TOKENS * NDIM * sizeof(float); // 45 MB
    unsigned short* xh = (unsigned short*)d_ws;
    float* part = (float*)((char*)d_ws + xh_bytes);

    awq_cvt_kernel<<<(TOKENS * KDIM / 4) / 256, 256, 0, stream>>>(x, xh);

    if (ws_size >= xh_bytes + part_bytes) {
        awq_gemm_mfma<false><<<dim3(NDIM / BLOCK_N, KSPLIT), BLOCK, 0, stream>>>(
            xh, qw, qz, sc, part);
        awq_reduce_kernel<<<(TOKENS * NDIM / 4) / 256, 256, 0, stream>>>(
            part, bias, out);
    } else {
        awq_init_kernel<<<dim3(NDIM / 256, TOKENS), 256, 0, stream>>>(bias, out);
        awq_gemm_mfma<true><<<dim3(NDIM / BLOCK_N, KSPLIT), BLOCK, 0, stream>>>(
            xh, qw, qz, sc, out);
    }
}

// Round 11
// 266.147 us; speedup vs baseline: 1.0515x; 1.0461x over previous
//
#include <hip/hip_runtime.h>
#include <hip/hip_bf16.h>

// QuantLinearAWQ: out[T,N] = x[T,K] @ ((q - z) * s)[K,N] + bias[N]
// T=32, K=4096, N=11008, group=128.
// R10 -> R11: R9/R10 (math-identical reorders of R8) fail with DIFFERENT
// small absmax -> schedule-dependent corruption from hoisted-register
// pipelining; that style is banned. R8's straight loop is the trusted core.
// This round: KSPLIT 32->8 (KCHUNK=512) to cut partials traffic 4x
// (90 -> 22.5 MB round-trip) + 4x smaller reduce. Outer group-loop (plain
// for, scalar s/z reloads) around the VERBATIM R8 inner body. 128-thread
// blocks, BLOCK_N=128 -> 688 blocks for balance.

#define TOKENS   32
#define KDIM     4096
#define NDIM     11008
#define GS       128
#define KSPLIT   8
#define KCHUNK   512               // 4 quant groups per k-block
#define BLOCK    128               // 2 waves
#define BLOCK_N  128               // 86 * 128 == 11008 exactly

typedef __attribute__((ext_vector_type(8))) _Float16 half8;  // MFMA A/B
typedef __attribute__((ext_vector_type(4))) float   floatx4; // MFMA C/D

// ---------- x fp32 -> fp16 (256 KB, L2-resident during gemm) ----------
__global__ __launch_bounds__(256) void awq_cvt_kernel(
    const float* __restrict__ x, unsigned short* __restrict__ xh)
{
    const int i = blockIdx.x * 256 + threadIdx.x;      // grid 128: 32768 float4s
    const float4 v = ((const float4*)x)[i];
    ushort4 o;
    o.x = __builtin_bit_cast(unsigned short, (_Float16)v.x);
    o.y = __builtin_bit_cast(unsigned short, (_Float16)v.y);
    o.z = __builtin_bit_cast(unsigned short, (_Float16)v.z);
    o.w = __builtin_bit_cast(unsigned short, (_Float16)v.w);
    ((ushort4*)xh)[i] = o;
}

// ---------- bias init (atomic-fallback path only) ----------
__global__ __launch_bounds__(256) void awq_init_kernel(
    const float* __restrict__ bias, float* __restrict__ out)
{
    const int n = blockIdx.x * 256 + threadIdx.x;      // grid (43, 32)
    out[blockIdx.y * NDIM + n] = bias[n];
}

// ---------- MFMA dequant-GEMM ----------
// A-frag: A[m=lane&15][k=quad*8+j]; C/D: col=lane&15, row=quad*4+reg.
// B symmetric to A. Column remap (R8-verified): MFMA-col c, tile nt ->
// memory column n = nb + 4*c + nt; one int4 per (k-row, lane) feeds 4 tiles.
template<bool ATOMIC>
__global__ __launch_bounds__(BLOCK) void awq_gemm_mfma(
    const unsigned short* __restrict__ xh,   // [T][K] fp16 bits
    const int*   __restrict__ qw,            // [K][N] codes
    const int*   __restrict__ qz,            // [K/GS][N]
    const float* __restrict__ sc,            // [K/GS][N]
    float*       __restrict__ dst)           // part [KSPLIT][T][N] or out [T][N]
{
    const int tid  = threadIdx.x;
    const int lane = tid & 63;
    const int wv   = tid >> 6;               // 0..1
    const int col  = lane & 15;
    const int quad = lane >> 4;              // 0..3
    const int nb   = blockIdx.x * BLOCK_N + wv * 64;
    const int nc   = nb + 4 * col;           // 4 consecutive columns per lane

    floatx4 acc[4][2];
    #pragma unroll
    for (int nt = 0; nt < 4; ++nt) {
        acc[nt][0] = (floatx4){0.f, 0.f, 0.f, 0.f};
        acc[nt][1] = (floatx4){0.f, 0.f, 0.f, 0.f};
    }

    // outer loop over the 4 quant groups of this k-chunk (plain for-loop,
    // scalar s/z reloads; inner body is byte-for-byte the R8 verified loop)
    for (int gi = 0; gi < KCHUNK / GS; ++gi) {
        const int g   = blockIdx.y * (KCHUNK / GS) + gi;
        const int kc0 = g * GS;

        // scalar s/z loads at the remapped columns; (q-8)-(z-8) == q-z
        float s[4], nzs[4];
        #pragma unroll
        for (int nt = 0; nt < 4; ++nt) {
            const int n  = nc + nt;
            const float sv = sc[(size_t)g * NDIM + n];
            const int   zv = qz[(size_t)g * NDIM + n];
            s[nt] = sv; nzs[nt] = -(float)zv * sv;
        }

        const int* qbase = qw + (size_t)(kc0 + quad * 8) * NDIM + nc;
        const unsigned short* xr0 = xh + (size_t)col * KDIM + kc0 + quad * 8;
        const unsigned short* xr1 = xr0 + 16 * KDIM;   // tokens 16-31

        #pragma unroll 2
        for (int ks = 0; ks < GS / 32; ++ks) {   // 4 k-steps of 32
            // 8 x dwordx4: 16B/lane, 256B contiguous per quad-row
            int4 q[8];
            #pragma unroll
            for (int j = 0; j < 8; ++j)
                q[j] = *(const int4*)(qbase + (size_t)(ks * 32 + j) * NDIM);

            const half8 a0 = *(const half8*)(xr0 + ks * 32);   // tokens 0-15
            const half8 a1 = *(const half8*)(xr1 + ks * 32);   // tokens 16-31

            half8 b0, b1, b2, b3;
            #pragma unroll
            for (int j = 0; j < 8; ++j) {
                b0[j] = (_Float16)fmaf((float)q[j].x, s[0], nzs[0]);
                b1[j] = (_Float16)fmaf((float)q[j].y, s[1], nzs[1]);
                b2[j] = (_Float16)fmaf((float)q[j].z, s[2], nzs[2]);
                b3[j] = (_Float16)fmaf((float)q[j].w, s[3], nzs[3]);
            }
            acc[0][0] = __builtin_amdgcn_mfma_f32_16x16x32_f16(a0, b0, acc[0][0], 0, 0, 0);
            acc[0][1] = __builtin_amdgcn_mfma_f32_16x16x32_f16(a1, b0, acc[0][1], 0, 0, 0);
            acc[1][0] = __builtin_amdgcn_mfma_f32_16x16x32_f16(a0, b1, acc[1][0], 0, 0, 0);
            acc[1][1] = __builtin_amdgcn_mfma_f32_16x16x32_f16(a1, b1, acc[1][1], 0, 0, 0);
            acc[2][0] = __builtin_amdgcn_mfma_f32_16x16x32_f16(a0, b2, acc[2][0], 0, 0, 0);
            acc[2][1] = __builtin_amdgcn_mfma_f32_16x16x32_f16(a1, b2, acc[2][1], 0, 0, 0);
            acc[3][0] = __builtin_amdgcn_mfma_f32_16x16x32_f16(a0, b3, acc[3][0], 0, 0, 0);
            acc[3][1] = __builtin_amdgcn_mfma_f32_16x16x32_f16(a1, b3, acc[3][1], 0, 0, 0);
        }
    }

    // token = h*16 + quad*4 + r; columns nc..nc+3 = tiles 0..3 -> float4
    if (ATOMIC) {
        #pragma unroll
        for (int h = 0; h < 2; ++h)
            #pragma unroll
            for (int r = 0; r < 4; ++r) {
                float* pp = dst + (size_t)(h * 16 + quad * 4 + r) * NDIM + nc;
                unsafeAtomicAdd(pp + 0, acc[0][h][r]);
                unsafeAtomicAdd(pp + 1, acc[1][h][r]);
                unsafeAtomicAdd(pp + 2, acc[2][h][r]);
                unsafeAtomicAdd(pp + 3, acc[3][h][r]);
            }
    } else {
        float* pbase = dst + (size_t)blockIdx.y * TOKENS * NDIM;
        #pragma unroll
        for (int h = 0; h < 2; ++h)
            #pragma unroll
            for (int r = 0; r < 4; ++r) {
                const float4 v = make_float4(acc[0][h][r], acc[1][h][r],
                                             acc[2][h][r], acc[3][h][r]);
                *(float4*)(pbase + (size_t)(h * 16 + quad * 4 + r) * NDIM + nc) = v;
            }
    }
}

// ---------- reduce KSPLIT partials + bias ----------
__global__ __launch_bounds__(256) void awq_reduce_kernel(
    const float* __restrict__ part,   // [KSPLIT][T][N]
    const float* __restrict__ bias,
    float*       __restrict__ out)    // [T][N]
{
    const int o = blockIdx.x * 256 + threadIdx.x;   // float4 idx, 88064 total
    const int t = o / (NDIM / 4);
    const int c = o - t * (NDIM / 4);
    const float4* p4 = (const float4*)part;
    float4 sum = ((const float4*)bias)[c];
    #pragma unroll
    for (int s = 0; s < KSPLIT; ++s) {
        const float4 v = p4[(size_t)(s * TOKENS + t) * (NDIM / 4) + c];
        sum.x += v.x; sum.y += v.y; sum.z += v.z; sum.w += v.w;
    }
    ((float4*)out)[o] = sum;
}

extern "C" void kernel_launch(void* const* d_in, const int* in_sizes, int n_in,
                              void* d_out, int out_size, void* d_ws, size_t ws_size,
                              hipStream_t stream) {
    const float* x    = (const float*)d_in[0];
    const int*   qw   = (const int*)  d_in[1];
    const int*   qz   = (const int*)  d_in[2];
    const float* sc   = (const float*)d_in[3];
    const float* bias = (const float*)d_in[4];
    float* out = (float*)d_out;

    const size_t xh_bytes   = 512 * 1024;  // 256 KB used, padded
    const size_t part_bytes = (size_t)KSPLIT * TOKENS * NDIM * sizeof(float); // 11.3 MB
    unsigned short* xh = (unsigned short*)d_ws;
    float* part = (float*)((char*)d_ws + xh_bytes);

    awq_cvt_kernel<<<(TOKENS * KDIM / 4) / 256, 256, 0, stream>>>(x, xh);

    if (ws_size >= xh_bytes + part_bytes) {
        awq_gemm_mfma<false><<<dim3(NDIM / BLOCK_N, KSPLIT), BLOCK, 0, stream>>>(
            xh, qw, qz, sc, part);
        awq_reduce_kernel<<<(TOKENS * NDIM / 4) / 256, 256, 0, stream>>>(
            part, bias, out);
    } else {
        awq_init_kernel<<<dim3(NDIM / 256, TOKENS), 256, 0, stream>>>(bias, out);
        awq_gemm_mfma<true><<<dim3(NDIM / BLOCK_N, KSPLIT), BLOCK, 0, stream>>>(
            xh, qw, qz, sc, out);
    }
}